// Round 4
// baseline (47.069 us; speedup 1.0000x reference)
//
#include <hip/hip_runtime.h>
#include <math.h>

constexpr int Hd = 128;   // hidden
constexpr int Nd = 64;    // state size
constexpr int Ld = 4096;  // sequence length
constexpr int Bd = 32;    // batch
constexpr int NBLK = Hd * 4;   // 512 blocks = (h, quarter-window)
constexpr int NL = 8;          // l-values per thread (stride 128 within 1024-window)

__device__ __forceinline__ float fracf(float x) { return x - floorf(x); }

// ---------------------------------------------------------------------------
// One kernel does everything.
// Phase 1 (all 512 blocks): block (h,part) builds K[h, part*1024 .. +1024) in
//   LDS (f32-only inner loop: HW sin/cos in revolutions + Chebyshev recurrence
//   over 8 l's per thread), then partial convolution vs all 32 batches:
//     partS[bid][b] = sum_{l in window} K[l] * data[b, L-1-l]
//     partK[bid]    = sum_{l in window} K[l]
// Barrier: device-scope release atomicAdd on counter.
// Phase 2 (blocks 0..31): spin-acquire until all 512 arrived, then block b
//   does gelu + GLU + output projection for batch b.
// ---------------------------------------------------------------------------
__global__ __launch_bounds__(256, 2) void k_all(
    const float* __restrict__ data,
    const float* __restrict__ W_in,
    const float* __restrict__ b_in,
    const float* __restrict__ log_dt,
    const float* __restrict__ log_A_real,
    const float* __restrict__ A_imag,
    const float* __restrict__ C_re,
    const float* __restrict__ C_im,
    const float* __restrict__ Dvec,
    const float* __restrict__ W_glu,
    const float* __restrict__ b_glu,
    const float* __restrict__ W_out,
    const float* __restrict__ b_out,
    float* __restrict__ partS,     // [NBLK][Bd]
    float* __restrict__ partK,     // [NBLK]
    unsigned* __restrict__ counter,
    float* __restrict__ out)
{
    const int bid  = blockIdx.x;
    const int h    = bid >> 2;
    const int part = bid & 3;
    const int t    = threadIdx.x;      // 0..255
    const int base = part * 1024;

    __shared__ float sC[Nd][8];        // btr,bti,Sr,Si | dreL2,fb,f1,pad
    __shared__ float sK[1024];
    __shared__ float sKs[4];
    __shared__ float sy[Hd];
    __shared__ float sz[2*Hd];
    __shared__ float sred[4];

    // ---- per-n setup (f64 only here) ----
    if (t < Nd) {
        const int n = t;
        float dt   = expf(log_dt[h]);
        float a_re = -expf(log_A_real[h*Nd + n]);
        float a_im = A_imag[h*Nd + n];
        float dre  = dt * a_re, dim = dt * a_im;
        float er1 = expf(dre);
        float s1, c1; sincosf(dim, &s1, &c1);
        float em1_re = er1*c1 - 1.0f;
        float em1_im = er1*s1;
        float inv  = 1.0f / (a_re*a_re + a_im*a_im);
        float q_re = (em1_re*a_re + em1_im*a_im) * inv;
        float q_im = (em1_im*a_re - em1_re*a_im) * inv;
        float cre = C_re[h*Nd + n], cim = C_im[h*Nd + n];
        float btr = cre*q_re - cim*q_im;
        float bti = cre*q_im + cim*q_re;

        float  dreL2 = dre * 1.4426950408889634f;                       // log2(e)
        double rev   = (double)dt * (double)a_im * 0.15915494309189535; // dim/2pi
        double fb_d  = rev * (double)base;  fb_d -= floor(fb_d);
        double f1_d  = rev - floor(rev);
        // S = exp(dtA * 128)
        float  er128 = exp2f(dreL2 * 128.0f);
        double p128  = rev * 128.0;  p128 -= floor(p128);
        float  fp    = (float)p128;
        float  Sr = er128 * __builtin_amdgcn_cosf(fp);
        float  Si = er128 * __builtin_amdgcn_sinf(fp);

        sC[n][0] = btr;   sC[n][1] = bti;        sC[n][2] = Sr;  sC[n][3] = Si;
        sC[n][4] = dreL2; sC[n][5] = (float)fb_d; sC[n][6] = (float)f1_d; sC[n][7] = 0.f;
    }
    __syncthreads();

    // ---- K generation: thread (grp, lb) handles n in [grp*32, +32),
    //      l = base + lb + 128*j, j = 0..7 ----
    const int   lb  = t & 127;
    const int   grp = t >> 7;
    const float lbf = (float)lb;
    const float l0f = (float)(base + lb);

    float acc[NL];
    #pragma unroll
    for (int j = 0; j < NL; ++j) acc[j] = 0.f;

    const int n0 = grp * 32;
    #pragma unroll 2
    for (int n = n0; n < n0 + 32; ++n) {
        float4 cA = *(const float4*)&sC[n][0];   // btr, bti, Sr, Si
        float4 cB = *(const float4*)&sC[n][4];   // dreL2, fb, f1, -
        float er = exp2f(cB.x * l0f);
        float ph = fracf(fmaf(cB.z, lbf, cB.y));
        float sn = __builtin_amdgcn_sinf(ph);    // sin(2*pi*ph)
        float cs = __builtin_amdgcn_cosf(ph);
        float pr = er*cs, pi = er*sn;
        float u  = cA.x*pr - cA.y*pi;            // Re(Bt * p^l0)
        float v  = cA.x*pi + cA.y*pr;            // Im(Bt * p^l0)
        float c1 = cA.z + cA.z;                  // 2*Re(S)
        float c2 = -fmaf(cA.z, cA.z, cA.w*cA.w); // -|S|^2
        float x0 = u;
        float x1 = fmaf(u, cA.z, -(v*cA.w));     // Re(Bt * p^l0 * S)
        acc[0] += x0;  acc[1] += x1;
        #pragma unroll
        for (int j = 2; j < NL; ++j) {
            float x2 = fmaf(c1, x1, c2*x0);      // Chebyshev step
            acc[j] += x2;
            x0 = x1;  x1 = x2;
        }
    }

    // assemble sK (group A writes, group B adds)
    if (t < 128) {
        #pragma unroll
        for (int j = 0; j < NL; ++j) sK[lb + 128*j] = 2.0f*acc[j];
    }
    __syncthreads();
    if (t >= 128) {
        #pragma unroll
        for (int j = 0; j < NL; ++j) sK[lb + 128*j] += 2.0f*acc[j];
    }

    // partial K-sum
    float ksl = 0.f;
    #pragma unroll
    for (int j = 0; j < NL; ++j) ksl += acc[j];
    ksl *= 2.0f;
    #pragma unroll
    for (int off = 32; off >= 1; off >>= 1) ksl += __shfl_xor(ksl, off);
    const int wave = t >> 6, lane = t & 63;
    if (lane == 0) sKs[wave] = ksl;
    __syncthreads();
    if (t == 0) partK[bid] = sKs[0] + sKs[1] + sKs[2] + sKs[3];

    // ---- partial convolution: wave w handles b = w*8 .. w*8+7 ----
    const float4* sK4 = (const float4*)sK;
    #pragma unroll
    for (int bi = 0; bi < 8; ++bi) {
        const int b = wave*8 + bi;
        const float* xb = data + (size_t)b * Ld;
        float s = 0.0f;
        #pragma unroll
        for (int j = 0; j < 4; ++j) {
            float4 kv = sK4[lane + 64*j];
            float4 xv = *(const float4*)(xb + (4092 - base - (lane + 64*j)*4));
            s += kv.x*xv.w + kv.y*xv.z + kv.z*xv.y + kv.w*xv.x;
        }
        #pragma unroll
        for (int off = 32; off >= 1; off >>= 1) s += __shfl_xor(s, off);
        if (lane == 0) partS[bid*Bd + b] = s;
    }

    // ---- device-scope arrival; only blocks 0..31 continue ----
    __syncthreads();
    if (t == 0) {
        __threadfence();   // release block's partS/partK to device scope
        __hip_atomic_fetch_add(counter, 1u, __ATOMIC_RELEASE, __HIP_MEMORY_SCOPE_AGENT);
    }
    if (bid >= Bd) return;
    if (t == 0) {
        while (__hip_atomic_load(counter, __ATOMIC_ACQUIRE, __HIP_MEMORY_SCOPE_AGENT)
               < (unsigned)NBLK)
            __builtin_amdgcn_s_sleep(2);
        __threadfence();   // acquire: invalidate stale cached lines
    }
    __syncthreads();

    // ---- tail for batch b = bid ----
    const int b = bid;
    if (t < Hd) {
        const int hh = t;
        float s  = partS[(hh*4+0)*Bd + b] + partS[(hh*4+1)*Bd + b]
                 + partS[(hh*4+2)*Bd + b] + partS[(hh*4+3)*Bd + b];
        float ks = partK[hh*4+0] + partK[hh*4+1] + partK[hh*4+2] + partK[hh*4+3];
        float w  = W_in[hh], bi2 = b_in[hh];
        float ulast = data[(size_t)b*Ld + (Ld - 1)] * w + bi2;
        float y  = w*s + bi2*ks + ulast*Dvec[hh];
        // gelu (tanh approx), tanh via exp
        float arg = 0.7978845608028654f*(y + 0.044715f*y*y*y);
        float e2  = __expf(2.0f*arg);
        float th  = 1.0f - 2.0f/(e2 + 1.0f);
        sy[hh] = 0.5f*y*(1.0f + th);
    }
    __syncthreads();

    float zz = b_glu[t];
    #pragma unroll 8
    for (int hh = 0; hh < Hd; ++hh)
        zz += sy[hh] * W_glu[hh*(2*Hd) + t];
    sz[t] = zz;
    __syncthreads();

    float g = 0.0f;
    if (t < Hd) {
        float sig = 1.0f / (1.0f + __expf(-sz[t + Hd]));
        g = sz[t] * sig * W_out[t];
    }
    #pragma unroll
    for (int off = 32; off >= 1; off >>= 1) g += __shfl_xor(g, off);
    if ((t & 63) == 0) sred[t >> 6] = g;
    __syncthreads();
    if (t == 0) out[b] = sred[0] + sred[1] + sred[2] + sred[3] + b_out[0];
}

// ---------------------------------------------------------------------------
extern "C" void kernel_launch(void* const* d_in, const int* in_sizes, int n_in,
                              void* d_out, int out_size, void* d_ws, size_t ws_size,
                              hipStream_t stream) {
    const float* data   = (const float*)d_in[0];
    const float* W_in   = (const float*)d_in[1];
    const float* b_in   = (const float*)d_in[2];
    const float* log_dt = (const float*)d_in[3];
    const float* log_A  = (const float*)d_in[4];
    const float* A_im   = (const float*)d_in[5];
    const float* C_re   = (const float*)d_in[6];
    const float* C_im   = (const float*)d_in[7];
    const float* Dvec   = (const float*)d_in[8];
    const float* W_glu  = (const float*)d_in[9];
    const float* b_glu  = (const float*)d_in[10];
    const float* W_out  = (const float*)d_in[11];
    const float* b_out  = (const float*)d_in[12];
    float* out = (float*)d_out;

    float*    partS   = (float*)d_ws;                    // NBLK*Bd floats = 64 KB
    float*    partK   = partS + (size_t)NBLK * Bd;       // NBLK floats
    unsigned* counter = (unsigned*)(partK + NBLK);

    hipMemsetAsync(counter, 0, sizeof(unsigned), stream);
    k_all<<<NBLK, 256, 0, stream>>>(data, W_in, b_in, log_dt, log_A, A_im,
                                    C_re, C_im, Dvec, W_glu, b_glu, W_out, b_out,
                                    partS, partK, counter, out);
}

// Round 5
// 19.049 us; speedup vs baseline: 2.4710x; 2.4710x over previous
//
#include <hip/hip_runtime.h>
#include <math.h>

constexpr int Hd = 128;   // hidden
constexpr int Nd = 64;    // state size
constexpr int Ld = 4096;  // sequence length
constexpr int Bd = 32;    // batch
constexpr int PARTS = 8;              // windows per h
constexpr int WIN   = Ld / PARTS;     // 512
constexpr int NL    = WIN / 64;       // 8 l-values per thread (stride 64)

__device__ __forceinline__ float fracf(float x) { return x - floorf(x); }

// ---------------------------------------------------------------------------
// Kernel A: block (h, part) builds K[h, part*512 .. +512) in LDS and computes
// the partial convolution against all 32 batches.
//   thread (wave wv, lane) handles n in [wv*16, +16), l = base+lane+64j, j<8
//   via stride-64 Chebyshev recurrence: x_{j+1} = 2Re(S) x_j - |S|^2 x_{j-1}.
// Phase in revolutions -> HW v_sin/v_cos; magnitude via exp2f. f32-only loop.
// ---------------------------------------------------------------------------
__global__ __launch_bounds__(256, 4) void k_fused(
    const float* __restrict__ log_dt,
    const float* __restrict__ log_A_real,
    const float* __restrict__ A_imag,
    const float* __restrict__ C_re,
    const float* __restrict__ C_im,
    const float* __restrict__ data,
    float* __restrict__ partS,     // [Hd*PARTS][Bd]
    float* __restrict__ partK)     // [Hd*PARTS]
{
    const int bid  = blockIdx.x;
    const int h    = bid >> 3;
    const int part = bid & 7;
    const int t    = threadIdx.x;      // 0..255
    const int base = part * WIN;

    __shared__ float sC[Nd][8];        // btr,bti,Sr,Si | dreL2,fb,f1,pad
    __shared__ float sKp[4][WIN];      // per-wave n-partial K
    __shared__ float sK[WIN];
    __shared__ float sKs[4];

    // ---- per-n setup (wave 0 only; f64 only here) ----
    if (t < Nd) {
        const int n = t;
        float dt   = expf(log_dt[h]);
        float a_re = -expf(log_A_real[h*Nd + n]);
        float a_im = A_imag[h*Nd + n];
        float dre  = dt * a_re, dim = dt * a_im;
        float er1 = expf(dre);
        float s1, c1; sincosf(dim, &s1, &c1);
        float em1_re = er1*c1 - 1.0f;
        float em1_im = er1*s1;
        float inv  = 1.0f / (a_re*a_re + a_im*a_im);
        float q_re = (em1_re*a_re + em1_im*a_im) * inv;
        float q_im = (em1_im*a_re - em1_re*a_im) * inv;
        float cre = C_re[h*Nd + n], cim = C_im[h*Nd + n];
        float btr = cre*q_re - cim*q_im;
        float bti = cre*q_im + cim*q_re;

        float  dreL2 = dre * 1.4426950408889634f;                       // log2(e)
        double rev   = (double)dt * (double)a_im * 0.15915494309189535; // dim/2pi
        double fb_d  = rev * (double)base;  fb_d -= floor(fb_d);
        double f1_d  = rev - floor(rev);
        // S = exp(dtA * 64)
        float  er64 = exp2f(dreL2 * 64.0f);
        double p64  = rev * 64.0;  p64 -= floor(p64);
        float  fp   = (float)p64;
        float  Sr = er64 * __builtin_amdgcn_cosf(fp);
        float  Si = er64 * __builtin_amdgcn_sinf(fp);

        sC[n][0] = btr;   sC[n][1] = bti;         sC[n][2] = Sr;          sC[n][3] = Si;
        sC[n][4] = dreL2; sC[n][5] = (float)fb_d; sC[n][6] = (float)f1_d; sC[n][7] = 0.f;
    }
    __syncthreads();

    const int wv   = t >> 6;           // 0..3  (n-group)
    const int lane = t & 63;
    const int n0   = wv * 16;
    const float lbf = (float)lane;
    const float l0f = (float)(base + lane);

    float acc[NL];
    #pragma unroll
    for (int j = 0; j < NL; ++j) acc[j] = 0.f;

    #pragma unroll 4
    for (int n = n0; n < n0 + 16; ++n) {
        float4 cA = *(const float4*)&sC[n][0];   // btr, bti, Sr, Si
        float4 cB = *(const float4*)&sC[n][4];   // dreL2, fb, f1, -
        float er = exp2f(cB.x * l0f);
        float ph = fracf(fmaf(cB.z, lbf, cB.y));
        float sn = __builtin_amdgcn_sinf(ph);    // sin(2*pi*ph)
        float cs = __builtin_amdgcn_cosf(ph);
        float pr = er*cs, pi = er*sn;
        float u  = cA.x*pr - cA.y*pi;            // Re(Bt p^l0)
        float v  = cA.x*pi + cA.y*pr;            // Im(Bt p^l0)
        float c1 = cA.z + cA.z;                  // 2 Re(S)
        float c2 = -fmaf(cA.z, cA.z, cA.w*cA.w); // -|S|^2
        float x0 = u;
        float x1 = fmaf(u, cA.z, -(v*cA.w));     // Re(Bt p^l0 S)
        acc[0] += x0;  acc[1] += x1;
        #pragma unroll
        for (int j = 2; j < NL; ++j) {
            float x2 = fmaf(c1, x1, c2*x0);
            acc[j] += x2;
            x0 = x1;  x1 = x2;
        }
    }

    // per-wave n-partial K into LDS
    #pragma unroll
    for (int j = 0; j < NL; ++j) sKp[wv][lane + 64*j] = acc[j];

    // block K-sum (for the b_in term)
    float ksl = 0.f;
    #pragma unroll
    for (int j = 0; j < NL; ++j) ksl += acc[j];
    ksl *= 2.0f;
    #pragma unroll
    for (int off = 32; off >= 1; off >>= 1) ksl += __shfl_xor(ksl, off);
    if (lane == 0) sKs[wv] = ksl;
    __syncthreads();
    if (t == 0) partK[bid] = sKs[0] + sKs[1] + sKs[2] + sKs[3];

    // assemble sK = 2 * sum over 4 n-groups (float4 chunks)
    if (t < WIN/4) {
        const float4* p0 = (const float4*)sKp[0];
        const float4* p1 = (const float4*)sKp[1];
        const float4* p2 = (const float4*)sKp[2];
        const float4* p3 = (const float4*)sKp[3];
        float4 a = p0[t], b = p1[t], c = p2[t], d = p3[t];
        float4 r;
        r.x = 2.0f*(a.x+b.x+c.x+d.x);
        r.y = 2.0f*(a.y+b.y+c.y+d.y);
        r.z = 2.0f*(a.z+b.z+c.z+d.z);
        r.w = 2.0f*(a.w+b.w+c.w+d.w);
        ((float4*)sK)[t] = r;
    }
    __syncthreads();

    // ---- partial convolution: wave wv handles b = wv*8 .. wv*8+7 ----
    // preload all x (reversed) first to hide L2 latency
    float4 xva[8], xvb[8];
    #pragma unroll
    for (int bi = 0; bi < 8; ++bi) {
        const float* xb = data + (size_t)(wv*8 + bi)*Ld + (Ld - 4 - base);
        xva[bi] = *(const float4*)(xb - 4*lane);
        xvb[bi] = *(const float4*)(xb - 4*(lane + 64));
    }
    const float4* sK4 = (const float4*)sK;
    float4 k0 = sK4[lane], k1 = sK4[lane + 64];
    #pragma unroll
    for (int bi = 0; bi < 8; ++bi) {
        float s = k0.x*xva[bi].w + k0.y*xva[bi].z + k0.z*xva[bi].y + k0.w*xva[bi].x
                + k1.x*xvb[bi].w + k1.y*xvb[bi].z + k1.z*xvb[bi].y + k1.w*xvb[bi].x;
        #pragma unroll
        for (int off = 32; off >= 1; off >>= 1) s += __shfl_xor(s, off);
        if (lane == 0) partS[bid*Bd + wv*8 + bi] = s;
    }
}

// ---------------------------------------------------------------------------
// Kernel B: per batch b (32 blocks, 512 threads):
//   y[h] = W_in[h]*s + b_in[h]*ks + u_last*D[h];  gelu
//   z = y @ W_glu + b_glu (GEMV split over 2 h-halves);
//   glu = z[:128]*sigmoid(z[128:]); out = glu.W_out + b_out
// ---------------------------------------------------------------------------
__global__ __launch_bounds__(512, 2) void k_tail(
    const float* __restrict__ data,
    const float* __restrict__ partS,
    const float* __restrict__ partK,
    const float* __restrict__ W_in,
    const float* __restrict__ b_in,
    const float* __restrict__ Dvec,
    const float* __restrict__ W_glu,
    const float* __restrict__ b_glu,
    const float* __restrict__ W_out,
    const float* __restrict__ b_out,
    float* __restrict__ out)
{
    const int b    = blockIdx.x;
    const int t    = threadIdx.x;       // 0..511
    const int j    = t & 255;           // z column
    const int half = t >> 8;            // h-range half
    __shared__ float sy[Hd];
    __shared__ float szp[2][2*Hd];
    __shared__ float sred[2];

    if (t < Hd) {
        const int hh = t;
        float s = 0.f, ks = 0.f;
        #pragma unroll
        for (int p = 0; p < PARTS; ++p) {
            s  += partS[(hh*PARTS + p)*Bd + b];
            ks += partK[hh*PARTS + p];
        }
        float w  = W_in[hh], bi2 = b_in[hh];
        float ulast = data[(size_t)b*Ld + (Ld - 1)] * w + bi2;
        float y  = w*s + bi2*ks + ulast*Dvec[hh];
        float arg = 0.7978845608028654f*(y + 0.044715f*y*y*y);
        float e2  = __expf(2.0f*arg);
        float th  = 1.0f - 2.0f/(e2 + 1.0f);
        sy[hh] = 0.5f*y*(1.0f + th);
    }
    __syncthreads();

    float zz = half ? 0.0f : b_glu[j];
    const int h0 = half * 64;
    #pragma unroll 16
    for (int hh = h0; hh < h0 + 64; ++hh)
        zz += sy[hh] * W_glu[hh*(2*Hd) + j];
    szp[half][j] = zz;
    __syncthreads();

    float g = 0.0f;
    if (t < Hd) {
        float zl = szp[0][t]      + szp[1][t];
        float zh = szp[0][t + Hd] + szp[1][t + Hd];
        float sig = 1.0f / (1.0f + __expf(-zh));
        g = zl * sig * W_out[t];
    }
    if (t < 2*Hd) {
        #pragma unroll
        for (int off = 32; off >= 1; off >>= 1) g += __shfl_xor(g, off);
        if ((t & 63) == 0) sred[t >> 6] = g;
    }
    __syncthreads();
    if (t == 0) out[b] = sred[0] + sred[1] + b_out[0];
}

// ---------------------------------------------------------------------------
extern "C" void kernel_launch(void* const* d_in, const int* in_sizes, int n_in,
                              void* d_out, int out_size, void* d_ws, size_t ws_size,
                              hipStream_t stream) {
    const float* data   = (const float*)d_in[0];
    const float* W_in   = (const float*)d_in[1];
    const float* b_in   = (const float*)d_in[2];
    const float* log_dt = (const float*)d_in[3];
    const float* log_A  = (const float*)d_in[4];
    const float* A_im   = (const float*)d_in[5];
    const float* C_re   = (const float*)d_in[6];
    const float* C_im   = (const float*)d_in[7];
    const float* Dvec   = (const float*)d_in[8];
    const float* W_glu  = (const float*)d_in[9];
    const float* b_glu  = (const float*)d_in[10];
    const float* W_out  = (const float*)d_in[11];
    const float* b_out  = (const float*)d_in[12];
    float* out = (float*)d_out;

    float* partS = (float*)d_ws;                        // Hd*PARTS*Bd = 128 KB
    float* partK = partS + (size_t)Hd*PARTS*Bd;         // Hd*PARTS floats

    k_fused<<<dim3(Hd*PARTS), 256, 0, stream>>>(log_dt, log_A, A_im, C_re, C_im,
                                                data, partS, partK);
    k_tail <<<Bd, 512, 0, stream>>>(data, partS, partK, W_in, b_in, Dvec,
                                    W_glu, b_glu, W_out, b_out, out);
}

// Round 6
// 17.502 us; speedup vs baseline: 2.6894x; 1.0884x over previous
//
#include <hip/hip_runtime.h>
#include <math.h>

constexpr int Hd = 128;   // hidden
constexpr int Nd = 64;    // state size
constexpr int Ld = 4096;  // sequence length
constexpr int Bd = 32;    // batch
constexpr int PARTS = 8;              // windows per h
constexpr int WIN   = Ld / PARTS;     // 512
constexpr int NL    = WIN / 64;       // 8 l-values per thread (stride 64)

__device__ __forceinline__ float fracf(float x) { return x - floorf(x); }

// ---------------------------------------------------------------------------
// Kernel A: block (h, part), 512 threads (8 waves). Wave wv owns n-group
// [wv*8, wv*8+8); lane covers l = base + lane + 64*j, j<8 via stride-64
// Chebyshev recurrence x_{j+1} = 2Re(S) x_j - |S|^2 x_{j-1}.
// Then partial convolution vs all 32 batches (wave wv -> b = wv*4..wv*4+3).
// 1024 blocks x 8 waves = 32 waves/CU at 4 blocks/CU (launch_bounds 512,8).
// ---------------------------------------------------------------------------
__global__ __launch_bounds__(512, 8) void k_fused(
    const float* __restrict__ log_dt,
    const float* __restrict__ log_A_real,
    const float* __restrict__ A_imag,
    const float* __restrict__ C_re,
    const float* __restrict__ C_im,
    const float* __restrict__ data,
    float* __restrict__ partS,     // [Bd][Hd*PARTS]  (transposed!)
    float* __restrict__ partK)     // [Hd*PARTS]
{
    const int bid  = blockIdx.x;
    const int h    = bid >> 3;
    const int part = bid & 7;
    const int t    = threadIdx.x;      // 0..511
    const int base = part * WIN;

    __shared__ float sC[Nd][8];        // btr,bti,Sr,Si | dreL2,fb,f1,pad
    __shared__ float sKp[8][WIN];      // per-wave n-partial K
    __shared__ float sK[WIN];
    __shared__ float sKs[8];

    // ---- per-n setup (wave 0 only; f64 only here) ----
    if (t < Nd) {
        const int n = t;
        float dt   = expf(log_dt[h]);
        float a_re = -expf(log_A_real[h*Nd + n]);
        float a_im = A_imag[h*Nd + n];
        float dre  = dt * a_re, dim = dt * a_im;
        float er1 = expf(dre);
        float s1, c1; sincosf(dim, &s1, &c1);
        float em1_re = er1*c1 - 1.0f;
        float em1_im = er1*s1;
        float inv  = 1.0f / (a_re*a_re + a_im*a_im);
        float q_re = (em1_re*a_re + em1_im*a_im) * inv;
        float q_im = (em1_im*a_re - em1_re*a_im) * inv;
        float cre = C_re[h*Nd + n], cim = C_im[h*Nd + n];
        float btr = cre*q_re - cim*q_im;
        float bti = cre*q_im + cim*q_re;

        float  dreL2 = dre * 1.4426950408889634f;                       // log2(e)
        double rev   = (double)dt * (double)a_im * 0.15915494309189535; // dim/2pi
        double fb_d  = rev * (double)base;  fb_d -= floor(fb_d);
        double f1_d  = rev - floor(rev);
        // S = exp(dtA * 64)
        float  er64 = exp2f(dreL2 * 64.0f);
        double p64  = rev * 64.0;  p64 -= floor(p64);
        float  fp   = (float)p64;
        float  Sr = er64 * __builtin_amdgcn_cosf(fp);
        float  Si = er64 * __builtin_amdgcn_sinf(fp);

        sC[n][0] = btr;   sC[n][1] = bti;         sC[n][2] = Sr;          sC[n][3] = Si;
        sC[n][4] = dreL2; sC[n][5] = (float)fb_d; sC[n][6] = (float)f1_d; sC[n][7] = 0.f;
    }
    __syncthreads();

    const int wv   = t >> 6;           // 0..7  (n-group)
    const int lane = t & 63;
    const int n0   = wv * 8;
    const float lbf = (float)lane;
    const float l0f = (float)(base + lane);

    float acc[NL];
    #pragma unroll
    for (int j = 0; j < NL; ++j) acc[j] = 0.f;

    #pragma unroll
    for (int n = n0; n < n0 + 8; ++n) {
        float4 cA = *(const float4*)&sC[n][0];   // btr, bti, Sr, Si
        float4 cB = *(const float4*)&sC[n][4];   // dreL2, fb, f1, -
        float er = exp2f(cB.x * l0f);
        float ph = fracf(fmaf(cB.z, lbf, cB.y));
        float sn = __builtin_amdgcn_sinf(ph);    // sin(2*pi*ph)
        float cs = __builtin_amdgcn_cosf(ph);
        float pr = er*cs, pi = er*sn;
        float u  = cA.x*pr - cA.y*pi;            // Re(Bt p^l0)
        float v  = cA.x*pi + cA.y*pr;            // Im(Bt p^l0)
        float c1 = cA.z + cA.z;                  // 2 Re(S)
        float c2 = -fmaf(cA.z, cA.z, cA.w*cA.w); // -|S|^2
        float x0 = u;
        float x1 = fmaf(u, cA.z, -(v*cA.w));     // Re(Bt p^l0 S)
        acc[0] += x0;  acc[1] += x1;
        #pragma unroll
        for (int j = 2; j < NL; ++j) {
            float x2 = fmaf(c1, x1, c2*x0);
            acc[j] += x2;
            x0 = x1;  x1 = x2;
        }
    }

    // per-wave n-partial K into LDS
    #pragma unroll
    for (int j = 0; j < NL; ++j) sKp[wv][lane + 64*j] = acc[j];

    // block K-sum (for the b_in term)
    float ksl = 0.f;
    #pragma unroll
    for (int j = 0; j < NL; ++j) ksl += acc[j];
    ksl *= 2.0f;
    #pragma unroll
    for (int off = 32; off >= 1; off >>= 1) ksl += __shfl_xor(ksl, off);
    if (lane == 0) sKs[wv] = ksl;
    __syncthreads();
    if (t == 0) {
        float pk = 0.f;
        #pragma unroll
        for (int g = 0; g < 8; ++g) pk += sKs[g];
        partK[bid] = pk;   // bid = h*8+part
    }

    // assemble sK = 2 * sum over 8 n-groups (float4 chunks; threads 0..127)
    if (t < WIN/4) {
        float4 r = make_float4(0.f, 0.f, 0.f, 0.f);
        #pragma unroll
        for (int g = 0; g < 8; ++g) {
            float4 a = ((const float4*)sKp[g])[t];
            r.x += a.x; r.y += a.y; r.z += a.z; r.w += a.w;
        }
        r.x *= 2.0f; r.y *= 2.0f; r.z *= 2.0f; r.w *= 2.0f;
        ((float4*)sK)[t] = r;
    }
    __syncthreads();

    // ---- partial convolution: wave wv handles b = wv*4 .. wv*4+3 ----
    float4 xva[4], xvb[4];
    #pragma unroll
    for (int bi = 0; bi < 4; ++bi) {
        const float* xb = data + (size_t)(wv*4 + bi)*Ld + (Ld - 4 - base);
        xva[bi] = *(const float4*)(xb - 4*lane);
        xvb[bi] = *(const float4*)(xb - 4*(lane + 64));
    }
    const float4* sK4 = (const float4*)sK;
    float4 k0 = sK4[lane], k1 = sK4[lane + 64];
    #pragma unroll
    for (int bi = 0; bi < 4; ++bi) {
        float s = k0.x*xva[bi].w + k0.y*xva[bi].z + k0.z*xva[bi].y + k0.w*xva[bi].x
                + k1.x*xvb[bi].w + k1.y*xvb[bi].z + k1.z*xvb[bi].y + k1.w*xvb[bi].x;
        #pragma unroll
        for (int off = 32; off >= 1; off >>= 1) s += __shfl_xor(s, off);
        if (lane == 0) partS[(size_t)(wv*4 + bi)*(Hd*PARTS) + bid] = s;
    }
}

// ---------------------------------------------------------------------------
// Kernel B: per batch b (32 blocks, 512 threads):
//   y[h] = W_in[h]*s + b_in[h]*ks + u_last*D[h];  gelu
//   z = y @ W_glu + b_glu (GEMV split over 2 h-halves);
//   glu = z[:128]*sigmoid(z[128:]); out = glu.W_out + b_out
// ---------------------------------------------------------------------------
__global__ __launch_bounds__(512) void k_tail(
    const float* __restrict__ data,
    const float* __restrict__ partS,   // [Bd][Hd*PARTS]
    const float* __restrict__ partK,   // [Hd*PARTS]
    const float* __restrict__ W_in,
    const float* __restrict__ b_in,
    const float* __restrict__ Dvec,
    const float* __restrict__ W_glu,
    const float* __restrict__ b_glu,
    const float* __restrict__ W_out,
    const float* __restrict__ b_out,
    float* __restrict__ out)
{
    const int b    = blockIdx.x;
    const int t    = threadIdx.x;       // 0..511
    const int j    = t & 255;           // z column
    const int half = t >> 8;            // h-range half
    __shared__ float sy[Hd];
    __shared__ float szp[2][2*Hd];
    __shared__ float sred[2];

    if (t < Hd) {
        const int hh = t;
        const float4* ps4 = (const float4*)(partS + (size_t)b*(Hd*PARTS) + hh*PARTS);
        const float4* pk4 = (const float4*)(partK + hh*PARTS);
        float4 s0 = ps4[0], s1 = ps4[1], k0 = pk4[0], k1 = pk4[1];
        float s  = s0.x+s0.y+s0.z+s0.w + s1.x+s1.y+s1.z+s1.w;
        float ks = k0.x+k0.y+k0.z+k0.w + k1.x+k1.y+k1.z+k1.w;
        float w  = W_in[hh], bi2 = b_in[hh];
        float ulast = data[(size_t)b*Ld + (Ld - 1)] * w + bi2;
        float y  = w*s + bi2*ks + ulast*Dvec[hh];
        float arg = 0.7978845608028654f*(y + 0.044715f*y*y*y);
        float e2  = __expf(2.0f*arg);
        float th  = 1.0f - 2.0f/(e2 + 1.0f);
        sy[hh] = 0.5f*y*(1.0f + th);
    }
    __syncthreads();

    float zz = half ? 0.0f : b_glu[j];
    const int h0 = half * 64;
    #pragma unroll 16
    for (int hh = h0; hh < h0 + 64; ++hh)
        zz += sy[hh] * W_glu[hh*(2*Hd) + j];
    szp[half][j] = zz;
    __syncthreads();

    float g = 0.0f;
    if (t < Hd) {
        float zl = szp[0][t]      + szp[1][t];
        float zh = szp[0][t + Hd] + szp[1][t + Hd];
        float sig = 1.0f / (1.0f + __expf(-zh));
        g = zl * sig * W_out[t];
    }
    if (t < 2*Hd) {
        #pragma unroll
        for (int off = 32; off >= 1; off >>= 1) g += __shfl_xor(g, off);
        if ((t & 63) == 0) sred[t >> 6] = g;
    }
    __syncthreads();
    if (t == 0) out[b] = sred[0] + sred[1] + b_out[0];
}

// ---------------------------------------------------------------------------
extern "C" void kernel_launch(void* const* d_in, const int* in_sizes, int n_in,
                              void* d_out, int out_size, void* d_ws, size_t ws_size,
                              hipStream_t stream) {
    const float* data   = (const float*)d_in[0];
    const float* W_in   = (const float*)d_in[1];
    const float* b_in   = (const float*)d_in[2];
    const float* log_dt = (const float*)d_in[3];
    const float* log_A  = (const float*)d_in[4];
    const float* A_im   = (const float*)d_in[5];
    const float* C_re   = (const float*)d_in[6];
    const float* C_im   = (const float*)d_in[7];
    const float* Dvec   = (const float*)d_in[8];
    const float* W_glu  = (const float*)d_in[9];
    const float* b_glu  = (const float*)d_in[10];
    const float* W_out  = (const float*)d_in[11];
    const float* b_out  = (const float*)d_in[12];
    float* out = (float*)d_out;

    float* partS = (float*)d_ws;                        // Bd*Hd*PARTS = 128 KB
    float* partK = partS + (size_t)Bd*Hd*PARTS;         // Hd*PARTS floats

    k_fused<<<dim3(Hd*PARTS), 512, 0, stream>>>(log_dt, log_A, A_im, C_re, C_im,
                                                data, partS, partK);
    k_tail <<<Bd, 512, 0, stream>>>(data, partS, partK, W_in, b_in, Dvec,
                                    W_glu, b_glu, W_out, b_out, out);
}